// Round 7
// baseline (2123.833 us; speedup 1.0000x reference)
//
#include <hip/hip_runtime.h>

// File-scope: forbid implicit fma contraction (keeps every a*b+c as two
// single-rounded IEEE ops, matching the numpy reference bit-for-bit).
#pragma clang fp contract(off)

#define NPOINT 2048
#define NSAMPLE 32
#define NPTS 8192
#define NB 4
#define CH 16
#define FPS_THREADS 512
#define PTS_PER_THREAD (NPTS / FPS_THREADS) /* 16 */
#define PAIRS (PTS_PER_THREAD / 2)          /* 8 */
#define FPS_WAVES (FPS_THREADS / 64)        /* 8 */
#define BQ_BLOCKS 252
#define BQ_WAVES (BQ_BLOCKS * 8) /* 2016 */

typedef unsigned long long u64;
typedef float v2f __attribute__((ext_vector_type(2)));

// Output layout (flat float32, concatenated in reference return order)
#define OFF_NEWXYZ 0
#define OFF_NEWPTS (NB * NPOINT * 3)                          /* 24576 */
#define OFF_IDX (OFF_NEWPTS + NB * NPOINT * NSAMPLE * CH)     /* 4218880 */
#define OFF_GXYZ (OFF_IDX + NB * NPOINT * NSAMPLE)            /* 4481024 */

template <int CTRL>
__device__ __forceinline__ float dpp_fmax(float v) {
  // bound_ctrl=true -> 0-fill; distances are >= 0 so 0 is a safe identity.
  int o = __builtin_amdgcn_update_dpp(0, __float_as_int(v), CTRL, 0xf, 0xf, true);
  return fmaxf(v, __int_as_float(o));
}

// ---------------- Ball-query per-query body (shared by both paths) ---------
__device__ __forceinline__ void write_slot(float* __restrict__ out,
                                           const float* __restrict__ base,
                                           int b, int qi, int s, int p,
                                           float4 r0, float qx, float qy,
                                           float qz) {
  float dx = __fsub_rn(r0.x, qx);
  float dy = __fsub_rn(r0.y, qy);
  float dz = __fsub_rn(r0.z, qz);
  size_t qs = (size_t)b * NPOINT + qi;
  out[OFF_IDX + qs * NSAMPLE + s] = (float)p;  // idx stored as float32
  float* g = out + OFF_GXYZ + (qs * NSAMPLE + s) * 3;
  g[0] = dx;
  g[1] = dy;
  g[2] = dz;
  const float* row = base + (size_t)p * CH;
  float4 r1 = *reinterpret_cast<const float4*>(row + 4);
  float4 r2 = *reinterpret_cast<const float4*>(row + 8);
  float4 r3 = *reinterpret_cast<const float4*>(row + 12);
  float* np_ = out + OFF_NEWPTS + (qs * NSAMPLE + s) * CH;
  *reinterpret_cast<float4*>(np_ + 0) = make_float4(dx, dy, dz, r0.w);
  *reinterpret_cast<float4*>(np_ + 4) = r1;
  *reinterpret_cast<float4*>(np_ + 8) = r2;
  *reinterpret_cast<float4*>(np_ + 12) = r3;
}

// R23 4-wide chunk-group scan (bit-identical outputs to the serial scan:
// writes gated by pos<NSAMPLE, cnt monotone, 'first' sticky -> up to 3
// extra processed chunks are output-invisible).
__device__ __forceinline__ void ballq_one(const float* __restrict__ in,
                                          float* __restrict__ out, int b,
                                          int qi, int lane) {
  const float* base = in + (size_t)b * NPTS * CH;
  const float* q = out + OFF_NEWXYZ + ((size_t)b * NPOINT + qi) * 3;
  float qx = q[0], qy = q[1], qz = q[2];
  // Mirror reference: d2 = sum(q*q) + sum(p*p) - 2*(q . p)
  float qn = __fadd_rn(__fadd_rn(__fmul_rn(qx, qx), __fmul_rn(qy, qy)),
                       __fmul_rn(qz, qz));
  int cnt = 0;
  int first = 0;
  bool have_first = false;
  for (int cg = 0; cg < NPTS / 64 && cnt < NSAMPLE; cg += 4) {
    float4 r[4];
#pragma unroll
    for (int u = 0; u < 4; ++u)
      r[u] = *reinterpret_cast<const float4*>(
          base + (size_t)((cg + u) * 64 + lane) * CH);
#pragma unroll
    for (int u = 0; u < 4; ++u) {
      const int chunk = cg + u;
      const int p = chunk * 64 + lane;
      const float4 r0 = r[u];
      float pn =
          __fadd_rn(__fadd_rn(__fmul_rn(r0.x, r0.x), __fmul_rn(r0.y, r0.y)),
                    __fmul_rn(r0.z, r0.z));
      float dot =
          __fadd_rn(__fadd_rn(__fmul_rn(qx, r0.x), __fmul_rn(qy, r0.y)),
                    __fmul_rn(qz, r0.z));
      float d2 = __fsub_rn(__fadd_rn(qn, pn), __fmul_rn(2.0f, dot));
      bool in_r = d2 < 1.0f;  // RADIUS^2
      unsigned long long mask = __ballot(in_r);
      if (!have_first && mask) {
        first = chunk * 64 + __builtin_ctzll(mask);
        have_first = true;
      }
      int pos = cnt + __popcll(mask & ((1ull << lane) - 1ull));
      if (in_r && pos < NSAMPLE)
        write_slot(out, base, b, qi, pos, p, r0, qx, qy, qz);
      cnt += __popcll(mask);
    }
  }
  if (cnt < NSAMPLE) {
    int s = cnt + lane;
    if (s < NSAMPLE) {
      float4 r0 = *reinterpret_cast<const float4*>(base + (size_t)first * CH);
      write_slot(out, base, b, qi, s, first, r0, qx, qy, qz);
    }
  }
}

// ---------------- R24 fused producer-consumer kernel -----------------------
// Grid = 4 fps blocks + 252 ballq blocks = 256 blocks; 156KB static LDS
// forces 1 block/CU -> all 256 blocks co-resident on the 256-CU chip (no
// spin-deadlock exposure; spinners own their CUs, so the R18 issue-stealing
// failure mode cannot recur).
//
// fps blocks (0..3): BYTE-IDENTICAL inner loop to the verified 1735us form
// (ledger: R18 +152, R19 +385, R20 +1100, R21 +410, R22 +620 -- every
// instruction-stream perturbation of this loop regressed; DO NOT TOUCH).
// Additions are off the critical dataflow:
//  - it%16==0, it>=16: threads 0..47 copy window [it-16,it) of newb (LDS,
//    visible since >=1 barrier ago) to global newxyz. Fire-and-forget; the
//    NEXT top-barrier's natural vmcnt drain completes them.
//  - it%16==1, it>16: tid0 release-stores progress[b]=it-1 (agent scope;
//    the barrier between stores and flag gives cross-thread ordering).
//  - after the loop: final window [2032,2048) + barrier + progress=2048.
// ballq blocks (4..255): 2016 waves, one query per wave per pass, qi-major
// order (g = qi*4+b, stride 2016). Wave spin-waits progress[b] > qi
// (acquire + s_sleep), then runs the exact R23 query body. Production
// (~4.7 q/us) << consumption capacity -> ballq rides entirely under fps's
// shadow; tail after fps end = last 64 queries ~= 5us.
// Tie-breaks unchanged (exact jnp.argmax lowest-index semantics).
__global__ __launch_bounds__(FPS_THREADS)
__attribute__((amdgpu_waves_per_eu(2))) void fused_kernel(
    const float* __restrict__ in, float* __restrict__ out,
    unsigned* __restrict__ prog) {
  __shared__ float4 lpxyz[NPTS];      // 128 KB; winner coords: 1 ds_read_b128
  __shared__ float newb[NPOINT * 3];  // 24 KB newxyz staging
  __shared__ alignas(16) u64 slots[2][FPS_WAVES];  // per-wave argmax keys

  const int tid = threadIdx.x;
  const int lane = tid & 63;

  if (blockIdx.x >= NB) {
    // ------------------ ballq consumer role ------------------
    const int slot = (blockIdx.x - NB) * 8 + (tid >> 6);  // 0..2015
    for (int g = slot; g < NB * NPOINT; g += BQ_WAVES) {
      const int qi = g >> 2;  // qi-major: unlocks in production order
      const int b = g & 3;
      for (;;) {  // wave-uniform spin (b, qi uniform across the wave)
        unsigned p = __hip_atomic_load(&prog[b], __ATOMIC_ACQUIRE,
                                       __HIP_MEMORY_SCOPE_AGENT);
        if (p > (unsigned)qi) break;
        __builtin_amdgcn_s_sleep(32);
      }
      ballq_one(in, out, b, qi, lane);
    }
    return;
  }

  // ------------------ fps producer role ------------------
  const int b = blockIdx.x;
  const int wv = tid >> 6;
  const float* base = in + (size_t)b * NPTS * CH;
  float* gnew = out + OFF_NEWXYZ + (size_t)b * NPOINT * 3;

  v2f pxv[PAIRS], pyv[PAIRS], pzv[PAIRS], dv[PAIRS];
#pragma unroll
  for (int jp = 0; jp < PAIRS; ++jp) {
    int p0 = tid * PTS_PER_THREAD + 2 * jp;
    float4 r0 = *reinterpret_cast<const float4*>(base + (size_t)p0 * CH);
    float4 r1 = *reinterpret_cast<const float4*>(base + (size_t)(p0 + 1) * CH);
    pxv[jp] = (v2f){r0.x, r1.x};
    pyv[jp] = (v2f){r0.y, r1.y};
    pzv[jp] = (v2f){r0.z, r1.z};
    lpxyz[p0] = r0;
    lpxyz[p0 + 1] = r1;
    dv[jp] = (v2f){__builtin_inff(), __builtin_inff()};
  }
  // Prime parity-0 slots: slot 0 = (+inf, idx 0) wins the first compare.
  if (tid < FPS_WAVES)
    slots[0][tid] = (tid == 0) ? (((u64)0x7f800000u << 32) | 8191u) : 0ull;

  for (int it = 0; it < NPOINT; ++it) {
    __syncthreads();  // separates slot writes (it-1) from reads (it);
                      // also drains the previous window's publish stores
    // Read all 8 wave keys (broadcast, 4x ds_read_b128), 7-compare u64 max.
    const ulonglong2* sp =
        reinterpret_cast<const ulonglong2*>(&slots[it & 1][0]);
    const ulonglong2 s01 = sp[0];
    const ulonglong2 s23 = sp[1];
    const ulonglong2 s45 = sp[2];
    const ulonglong2 s67 = sp[3];
    u64 ka = (s01.y > s01.x) ? s01.y : s01.x;
    u64 kb = (s23.y > s23.x) ? s23.y : s23.x;
    u64 kc = (s45.y > s45.x) ? s45.y : s45.x;
    u64 kd = (s67.y > s67.x) ? s67.y : s67.x;
    ka = (kb > ka) ? kb : ka;
    kc = (kd > kc) ? kd : kc;
    const u64 k = (kc > ka) ? kc : ka;
    const int gi = 8191 - (int)(unsigned)k;  // low 32 bits = 8191-idx
    // Winner coords: broadcast LDS read.
    const float4 g = lpxyz[gi];
    const float gx = g.x, gy = g.y, gz = g.z;
    if (tid == 0) {
      newb[it * 3 + 0] = gx;
      newb[it * 3 + 1] = gy;
      newb[it * 3 + 2] = gz;
    }
    // Windowed publish (off the critical dataflow; see header comment).
    if ((it & 15) == 0 && it >= 16 && tid < 48)
      gnew[(it - 16) * 3 + tid] = newb[(it - 16) * 3 + tid];
    if ((it & 15) == 1 && it > 16 && tid == 0)
      __hip_atomic_store(&prog[b], (unsigned)(it - 1), __ATOMIC_RELEASE,
                         __HIP_MEMORY_SCOPE_AGENT);
    // Distance update (packed pairs; exact IEEE per-element) + in-loop
    // pair-granular tracking (bestjp + bestx; hidden under loop ILP).
    float bestv = -1.0f;
    float bestx = -1.0f;
    int bestjp = 0;
#pragma unroll
    for (int jp = 0; jp < PAIRS; ++jp) {
      v2f dx = pxv[jp] - gx;
      v2f dy = pyv[jp] - gy;
      v2f dz = pzv[jp] - gz;
      v2f nd = (dx * dx + dy * dy) + dz * dz;
      v2f dn = {fminf(dv[jp].x, nd.x), fminf(dv[jp].y, nd.y)};
      dv[jp] = dn;
      float pm = fmaxf(dn.x, dn.y);
      bool t = pm > bestv;  // strict: lowest jp wins ties
      bestjp = t ? jp : bestjp;
      bestx = t ? dn.x : bestx;
      bestv = fmaxf(bestv, pm);
    }
    // Within-pair parity: .x first (lower index) on ties.
    const int bestj = 2 * bestjp + ((bestx == bestv) ? 0 : 1);
    const unsigned besti = (unsigned)(tid * PTS_PER_THREAD + bestj);
    // Wave max via 6 DPP rounds -> lane 63; ballot -> lowest matching lane.
    float wm = bestv;
    wm = dpp_fmax<0x111>(wm);  // row_shr:1
    wm = dpp_fmax<0x112>(wm);  // row_shr:2
    wm = dpp_fmax<0x114>(wm);  // row_shr:4
    wm = dpp_fmax<0x118>(wm);  // row_shr:8
    wm = dpp_fmax<0x142>(wm);  // row_bcast15
    wm = dpp_fmax<0x143>(wm);  // row_bcast31
    const float swm =
        __int_as_float(__builtin_amdgcn_readlane(__float_as_int(wm), 63));
    const u64 wbal = __ballot(bestv == swm);
    const int wl = (int)__builtin_ctzll(wbal);
    if (lane == wl) {  // tiny tail: pack + one ds_write_b64
      slots[(it + 1) & 1][wv] =
          ((u64)__float_as_uint(bestv) << 32) | (8191u - besti);
    }
  }
  __syncthreads();
  // Final window [2032, 2048): store, drain via barrier, release.
  if (tid < 48) gnew[2032 * 3 + tid] = newb[2032 * 3 + tid];
  __syncthreads();
  if (tid == 0)
    __hip_atomic_store(&prog[b], (unsigned)NPOINT, __ATOMIC_RELEASE,
                       __HIP_MEMORY_SCOPE_AGENT);
}

// ---------------- Fallback pair (used only if ws_size < 16) ----------------
__global__ __launch_bounds__(FPS_THREADS)
__attribute__((amdgpu_waves_per_eu(2))) void fps_kernel(
    const float* __restrict__ in, float* __restrict__ out) {
  __shared__ float4 lpxyz[NPTS];
  __shared__ float newb[NPOINT * 3];
  __shared__ alignas(16) u64 slots[2][FPS_WAVES];
  const int b = blockIdx.x;
  const int tid = threadIdx.x;
  const int lane = tid & 63;
  const int wv = tid >> 6;
  const float* base = in + (size_t)b * NPTS * CH;
  v2f pxv[PAIRS], pyv[PAIRS], pzv[PAIRS], dv[PAIRS];
#pragma unroll
  for (int jp = 0; jp < PAIRS; ++jp) {
    int p0 = tid * PTS_PER_THREAD + 2 * jp;
    float4 r0 = *reinterpret_cast<const float4*>(base + (size_t)p0 * CH);
    float4 r1 = *reinterpret_cast<const float4*>(base + (size_t)(p0 + 1) * CH);
    pxv[jp] = (v2f){r0.x, r1.x};
    pyv[jp] = (v2f){r0.y, r1.y};
    pzv[jp] = (v2f){r0.z, r1.z};
    lpxyz[p0] = r0;
    lpxyz[p0 + 1] = r1;
    dv[jp] = (v2f){__builtin_inff(), __builtin_inff()};
  }
  if (tid < FPS_WAVES)
    slots[0][tid] = (tid == 0) ? (((u64)0x7f800000u << 32) | 8191u) : 0ull;
  for (int it = 0; it < NPOINT; ++it) {
    __syncthreads();
    const ulonglong2* sp =
        reinterpret_cast<const ulonglong2*>(&slots[it & 1][0]);
    const ulonglong2 s01 = sp[0];
    const ulonglong2 s23 = sp[1];
    const ulonglong2 s45 = sp[2];
    const ulonglong2 s67 = sp[3];
    u64 ka = (s01.y > s01.x) ? s01.y : s01.x;
    u64 kb = (s23.y > s23.x) ? s23.y : s23.x;
    u64 kc = (s45.y > s45.x) ? s45.y : s45.x;
    u64 kd = (s67.y > s67.x) ? s67.y : s67.x;
    ka = (kb > ka) ? kb : ka;
    kc = (kd > kc) ? kd : kc;
    const u64 k = (kc > ka) ? kc : ka;
    const int gi = 8191 - (int)(unsigned)k;
    const float4 g = lpxyz[gi];
    const float gx = g.x, gy = g.y, gz = g.z;
    if (tid == 0) {
      newb[it * 3 + 0] = gx;
      newb[it * 3 + 1] = gy;
      newb[it * 3 + 2] = gz;
    }
    float bestv = -1.0f;
    float bestx = -1.0f;
    int bestjp = 0;
#pragma unroll
    for (int jp = 0; jp < PAIRS; ++jp) {
      v2f dx = pxv[jp] - gx;
      v2f dy = pyv[jp] - gy;
      v2f dz = pzv[jp] - gz;
      v2f nd = (dx * dx + dy * dy) + dz * dz;
      v2f dn = {fminf(dv[jp].x, nd.x), fminf(dv[jp].y, nd.y)};
      dv[jp] = dn;
      float pm = fmaxf(dn.x, dn.y);
      bool t = pm > bestv;
      bestjp = t ? jp : bestjp;
      bestx = t ? dn.x : bestx;
      bestv = fmaxf(bestv, pm);
    }
    const int bestj = 2 * bestjp + ((bestx == bestv) ? 0 : 1);
    const unsigned besti = (unsigned)(tid * PTS_PER_THREAD + bestj);
    float wm = bestv;
    wm = dpp_fmax<0x111>(wm);
    wm = dpp_fmax<0x112>(wm);
    wm = dpp_fmax<0x114>(wm);
    wm = dpp_fmax<0x118>(wm);
    wm = dpp_fmax<0x142>(wm);
    wm = dpp_fmax<0x143>(wm);
    const float swm =
        __int_as_float(__builtin_amdgcn_readlane(__float_as_int(wm), 63));
    const u64 wbal = __ballot(bestv == swm);
    const int wl = (int)__builtin_ctzll(wbal);
    if (lane == wl) {
      slots[(it + 1) & 1][wv] =
          ((u64)__float_as_uint(bestv) << 32) | (8191u - besti);
    }
  }
  __syncthreads();
  float* ob = out + OFF_NEWXYZ + (size_t)b * NPOINT * 3;
  for (int i = tid; i < NPOINT * 3; i += FPS_THREADS) ob[i] = newb[i];
}

__global__ __launch_bounds__(256) void ballq_kernel(
    const float* __restrict__ in, float* __restrict__ out) {
  const int lane = threadIdx.x & 63;
  const int qid = blockIdx.x * 4 + (threadIdx.x >> 6);
  ballq_one(in, out, qid >> 11, qid & 2047, lane);
}

extern "C" void kernel_launch(void* const* d_in, const int* in_sizes, int n_in,
                              void* d_out, int out_size, void* d_ws,
                              size_t ws_size, hipStream_t stream) {
  (void)in_sizes;
  (void)n_in;
  (void)out_size;
  const float* in = (const float*)d_in[0];
  float* out = (float*)d_out;
  if (d_ws != nullptr && ws_size >= NB * sizeof(unsigned)) {
    unsigned* prog = (unsigned*)d_ws;
    hipMemsetAsync(prog, 0, NB * sizeof(unsigned), stream);
    fused_kernel<<<NB + BQ_BLOCKS, FPS_THREADS, 0, stream>>>(in, out, prog);
  } else {
    fps_kernel<<<NB, FPS_THREADS, 0, stream>>>(in, out);
    ballq_kernel<<<(NB * NPOINT) / 4, 256, 0, stream>>>(in, out);
  }
}

// Round 8
// 1910.277 us; speedup vs baseline: 1.1118x; 1.1118x over previous
//
#include <hip/hip_runtime.h>

// File-scope: forbid implicit fma contraction (keeps every a*b+c as two
// single-rounded IEEE ops, matching the numpy reference bit-for-bit).
#pragma clang fp contract(off)

#define NPOINT 2048
#define NSAMPLE 32
#define NPTS 8192
#define NB 4
#define CH 16
#define FPS_THREADS 512
#define PTS_PER_THREAD (NPTS / FPS_THREADS) /* 16 */
#define PAIRS (PTS_PER_THREAD / 2)          /* 8 */
#define FPS_WAVES (FPS_THREADS / 64)        /* 8 */
#define BQ_BLOCKS 252
#define BQ_WAVES (BQ_BLOCKS * 8) /* 2016 */

typedef unsigned long long u64;
typedef float v2f __attribute__((ext_vector_type(2)));

// Output layout (flat float32, concatenated in reference return order)
#define OFF_NEWXYZ 0
#define OFF_NEWPTS (NB * NPOINT * 3)                          /* 24576 */
#define OFF_IDX (OFF_NEWPTS + NB * NPOINT * NSAMPLE * CH)     /* 4218880 */
#define OFF_GXYZ (OFF_IDX + NB * NPOINT * NSAMPLE)            /* 4481024 */

template <int CTRL>
__device__ __forceinline__ float dpp_fmax(float v) {
  // bound_ctrl=true -> 0-fill; distances are >= 0 so 0 is a safe identity.
  int o = __builtin_amdgcn_update_dpp(0, __float_as_int(v), CTRL, 0xf, 0xf, true);
  return fmaxf(v, __int_as_float(o));
}

// Cache-bypassing (sc1 / agent-scope, relaxed) accessors. On gfx950 the
// per-XCD L2s are NOT cross-coherent: agent ACQUIRE loads emit cache
// invalidations and agent RELEASE stores emit L2 writebacks (R24's +370us
// producer convoy + 8.8MB refetch traffic). Relaxed agent atomics set the
// sc bits only -- they read/write the agent coherence point directly with
// NO invalidate/writeback side effects. Ordering comes from barriers.
__device__ __forceinline__ float ld_sc1(const float* p) {
  return __hip_atomic_load(p, __ATOMIC_RELAXED, __HIP_MEMORY_SCOPE_AGENT);
}
__device__ __forceinline__ void st_sc1(float* p, float v) {
  __hip_atomic_store(p, v, __ATOMIC_RELAXED, __HIP_MEMORY_SCOPE_AGENT);
}

// ---------------- Ball-query per-query body (shared by both paths) ---------
__device__ __forceinline__ void write_slot(float* __restrict__ out,
                                           const float* __restrict__ base,
                                           int b, int qi, int s, int p,
                                           float4 r0, float qx, float qy,
                                           float qz) {
  float dx = __fsub_rn(r0.x, qx);
  float dy = __fsub_rn(r0.y, qy);
  float dz = __fsub_rn(r0.z, qz);
  size_t qs = (size_t)b * NPOINT + qi;
  out[OFF_IDX + qs * NSAMPLE + s] = (float)p;  // idx stored as float32
  float* g = out + OFF_GXYZ + (qs * NSAMPLE + s) * 3;
  g[0] = dx;
  g[1] = dy;
  g[2] = dz;
  const float* row = base + (size_t)p * CH;
  float4 r1 = *reinterpret_cast<const float4*>(row + 4);
  float4 r2 = *reinterpret_cast<const float4*>(row + 8);
  float4 r3 = *reinterpret_cast<const float4*>(row + 12);
  float* np_ = out + OFF_NEWPTS + (qs * NSAMPLE + s) * CH;
  *reinterpret_cast<float4*>(np_ + 0) = make_float4(dx, dy, dz, r0.w);
  *reinterpret_cast<float4*>(np_ + 4) = r1;
  *reinterpret_cast<float4*>(np_ + 8) = r2;
  *reinterpret_cast<float4*>(np_ + 12) = r3;
}

// R23 4-wide chunk-group scan (bit-identical outputs to the serial scan:
// writes gated by pos<NSAMPLE, cnt monotone, 'first' sticky -> up to 3
// extra processed chunks are output-invisible). Query coords are read
// sc1 (cache-bypassing): they are cross-workgroup data in the fused path,
// and bypassing means no stale-L1/L2 hazard without any invalidation cost.
__device__ __forceinline__ void ballq_one(const float* __restrict__ in,
                                          float* __restrict__ out, int b,
                                          int qi, int lane) {
  const float* base = in + (size_t)b * NPTS * CH;
  const float* q = out + OFF_NEWXYZ + ((size_t)b * NPOINT + qi) * 3;
  float qx = ld_sc1(q + 0), qy = ld_sc1(q + 1), qz = ld_sc1(q + 2);
  // Mirror reference: d2 = sum(q*q) + sum(p*p) - 2*(q . p)
  float qn = __fadd_rn(__fadd_rn(__fmul_rn(qx, qx), __fmul_rn(qy, qy)),
                       __fmul_rn(qz, qz));
  int cnt = 0;
  int first = 0;
  bool have_first = false;
  for (int cg = 0; cg < NPTS / 64 && cnt < NSAMPLE; cg += 4) {
    float4 r[4];
#pragma unroll
    for (int u = 0; u < 4; ++u)
      r[u] = *reinterpret_cast<const float4*>(
          base + (size_t)((cg + u) * 64 + lane) * CH);
#pragma unroll
    for (int u = 0; u < 4; ++u) {
      const int chunk = cg + u;
      const int p = chunk * 64 + lane;
      const float4 r0 = r[u];
      float pn =
          __fadd_rn(__fadd_rn(__fmul_rn(r0.x, r0.x), __fmul_rn(r0.y, r0.y)),
                    __fmul_rn(r0.z, r0.z));
      float dot =
          __fadd_rn(__fadd_rn(__fmul_rn(qx, r0.x), __fmul_rn(qy, r0.y)),
                    __fmul_rn(qz, r0.z));
      float d2 = __fsub_rn(__fadd_rn(qn, pn), __fmul_rn(2.0f, dot));
      bool in_r = d2 < 1.0f;  // RADIUS^2
      unsigned long long mask = __ballot(in_r);
      if (!have_first && mask) {
        first = chunk * 64 + __builtin_ctzll(mask);
        have_first = true;
      }
      int pos = cnt + __popcll(mask & ((1ull << lane) - 1ull));
      if (in_r && pos < NSAMPLE)
        write_slot(out, base, b, qi, pos, p, r0, qx, qy, qz);
      cnt += __popcll(mask);
    }
  }
  if (cnt < NSAMPLE) {
    int s = cnt + lane;
    if (s < NSAMPLE) {
      float4 r0 = *reinterpret_cast<const float4*>(base + (size_t)first * CH);
      write_slot(out, base, b, qi, s, first, r0, qx, qy, qz);
    }
  }
}

// ---------------- R25 fused producer-consumer kernel -----------------------
// Grid = 4 fps blocks + 252 ballq blocks = 256 blocks; 156KB static LDS
// forces 1 block/CU -> all 256 blocks co-resident (spinners own their CUs).
//
// fps blocks (0..3): BYTE-IDENTICAL inner loop to the verified 1735us form
// (ledger: R18 +152, R19 +385, R20 +1100, R21 +410, R22 +620 -- every
// instruction-stream perturbation of this loop regressed; DO NOT TOUCH).
// Publish protocol (all relaxed sc1, NO fences -> no wbl2/inv, the R24 bug):
//  - it%16==0, it>=16: tids 0..47 sc1-store window [it-16,it) of newb to
//    global newxyz. The next __syncthreads' vmcnt(0) drain completes them.
//  - it%16==1, it>16: tid0 sc1-stores prog[b]=it-1. Data stores completed
//    at the barrier between; flag issued after -> ordering by barrier.
//  - after the loop: final window + barrier + prog=2048.
// ballq blocks (4..255): 2016 waves, qi-major (g=qi*4+b, stride 2016) so
// queries unlock in production order. Spin = relaxed sc1 poll + adaptive
// deficit-proportional sleep (~0.43us quantum, capped ~27us): <100 polls/us
// chip-wide vs R24's ~2400 invalidating polls/us.
__global__ __launch_bounds__(FPS_THREADS)
__attribute__((amdgpu_waves_per_eu(2))) void fused_kernel(
    const float* __restrict__ in, float* __restrict__ out,
    unsigned* __restrict__ prog) {
  __shared__ float4 lpxyz[NPTS];      // 128 KB; winner coords: 1 ds_read_b128
  __shared__ float newb[NPOINT * 3];  // 24 KB newxyz staging
  __shared__ alignas(16) u64 slots[2][FPS_WAVES];  // per-wave argmax keys

  const int tid = threadIdx.x;
  const int lane = tid & 63;

  if (blockIdx.x >= NB) {
    // ------------------ ballq consumer role ------------------
    const int slot = (blockIdx.x - NB) * 8 + (tid >> 6);  // 0..2015
    for (int g = slot; g < NB * NPOINT; g += BQ_WAVES) {
      const int qi = g >> 2;  // qi-major: unlocks in production order
      const int b = g & 3;
      for (;;) {  // wave-uniform spin (b, qi uniform across the wave)
        unsigned p = __hip_atomic_load(&prog[b], __ATOMIC_RELAXED,
                                       __HIP_MEMORY_SCOPE_AGENT);
        if (p > (unsigned)qi) break;
        // Deficit-proportional sleep: production ~0.85us/query; nap 0.43us
        // per outstanding query (2x poll margin), capped at ~27us.
        unsigned d = (unsigned)qi - p + 1u;
        unsigned naps = d >> 1;
        if (naps == 0u) naps = 1u;
        if (naps > 64u) naps = 64u;
        for (unsigned i = 0; i < naps; ++i) __builtin_amdgcn_s_sleep(16);
      }
      ballq_one(in, out, b, qi, lane);
    }
    return;
  }

  // ------------------ fps producer role ------------------
  const int b = blockIdx.x;
  const int wv = tid >> 6;
  const float* base = in + (size_t)b * NPTS * CH;
  float* gnew = out + OFF_NEWXYZ + (size_t)b * NPOINT * 3;

  v2f pxv[PAIRS], pyv[PAIRS], pzv[PAIRS], dv[PAIRS];
#pragma unroll
  for (int jp = 0; jp < PAIRS; ++jp) {
    int p0 = tid * PTS_PER_THREAD + 2 * jp;
    float4 r0 = *reinterpret_cast<const float4*>(base + (size_t)p0 * CH);
    float4 r1 = *reinterpret_cast<const float4*>(base + (size_t)(p0 + 1) * CH);
    pxv[jp] = (v2f){r0.x, r1.x};
    pyv[jp] = (v2f){r0.y, r1.y};
    pzv[jp] = (v2f){r0.z, r1.z};
    lpxyz[p0] = r0;
    lpxyz[p0 + 1] = r1;
    dv[jp] = (v2f){__builtin_inff(), __builtin_inff()};
  }
  // Prime parity-0 slots: slot 0 = (+inf, idx 0) wins the first compare.
  if (tid < FPS_WAVES)
    slots[0][tid] = (tid == 0) ? (((u64)0x7f800000u << 32) | 8191u) : 0ull;

  for (int it = 0; it < NPOINT; ++it) {
    __syncthreads();  // separates slot writes (it-1) from reads (it);
                      // also drains the previous window's publish stores
    // Read all 8 wave keys (broadcast, 4x ds_read_b128), 7-compare u64 max.
    const ulonglong2* sp =
        reinterpret_cast<const ulonglong2*>(&slots[it & 1][0]);
    const ulonglong2 s01 = sp[0];
    const ulonglong2 s23 = sp[1];
    const ulonglong2 s45 = sp[2];
    const ulonglong2 s67 = sp[3];
    u64 ka = (s01.y > s01.x) ? s01.y : s01.x;
    u64 kb = (s23.y > s23.x) ? s23.y : s23.x;
    u64 kc = (s45.y > s45.x) ? s45.y : s45.x;
    u64 kd = (s67.y > s67.x) ? s67.y : s67.x;
    ka = (kb > ka) ? kb : ka;
    kc = (kd > kc) ? kd : kc;
    const u64 k = (kc > ka) ? kc : ka;
    const int gi = 8191 - (int)(unsigned)k;  // low 32 bits = 8191-idx
    // Winner coords: broadcast LDS read.
    const float4 g = lpxyz[gi];
    const float gx = g.x, gy = g.y, gz = g.z;
    if (tid == 0) {
      newb[it * 3 + 0] = gx;
      newb[it * 3 + 1] = gy;
      newb[it * 3 + 2] = gz;
    }
    // Windowed publish (off the critical dataflow; relaxed sc1, no fences).
    if ((it & 15) == 0 && it >= 16 && tid < 48)
      st_sc1(&gnew[(it - 16) * 3 + tid], newb[(it - 16) * 3 + tid]);
    if ((it & 15) == 1 && it > 16 && tid == 0)
      __hip_atomic_store(&prog[b], (unsigned)(it - 1), __ATOMIC_RELAXED,
                         __HIP_MEMORY_SCOPE_AGENT);
    // Distance update (packed pairs; exact IEEE per-element) + in-loop
    // pair-granular tracking (bestjp + bestx; hidden under loop ILP).
    float bestv = -1.0f;
    float bestx = -1.0f;
    int bestjp = 0;
#pragma unroll
    for (int jp = 0; jp < PAIRS; ++jp) {
      v2f dx = pxv[jp] - gx;
      v2f dy = pyv[jp] - gy;
      v2f dz = pzv[jp] - gz;
      v2f nd = (dx * dx + dy * dy) + dz * dz;
      v2f dn = {fminf(dv[jp].x, nd.x), fminf(dv[jp].y, nd.y)};
      dv[jp] = dn;
      float pm = fmaxf(dn.x, dn.y);
      bool t = pm > bestv;  // strict: lowest jp wins ties
      bestjp = t ? jp : bestjp;
      bestx = t ? dn.x : bestx;
      bestv = fmaxf(bestv, pm);
    }
    // Within-pair parity: .x first (lower index) on ties.
    const int bestj = 2 * bestjp + ((bestx == bestv) ? 0 : 1);
    const unsigned besti = (unsigned)(tid * PTS_PER_THREAD + bestj);
    // Wave max via 6 DPP rounds -> lane 63; ballot -> lowest matching lane.
    float wm = bestv;
    wm = dpp_fmax<0x111>(wm);  // row_shr:1
    wm = dpp_fmax<0x112>(wm);  // row_shr:2
    wm = dpp_fmax<0x114>(wm);  // row_shr:4
    wm = dpp_fmax<0x118>(wm);  // row_shr:8
    wm = dpp_fmax<0x142>(wm);  // row_bcast15
    wm = dpp_fmax<0x143>(wm);  // row_bcast31
    const float swm =
        __int_as_float(__builtin_amdgcn_readlane(__float_as_int(wm), 63));
    const u64 wbal = __ballot(bestv == swm);
    const int wl = (int)__builtin_ctzll(wbal);
    if (lane == wl) {  // tiny tail: pack + one ds_write_b64
      slots[(it + 1) & 1][wv] =
          ((u64)__float_as_uint(bestv) << 32) | (8191u - besti);
    }
  }
  __syncthreads();
  // Final window [2032, 2048): sc1 store, drain via barrier, flag.
  if (tid < 48) st_sc1(&gnew[2032 * 3 + tid], newb[2032 * 3 + tid]);
  __syncthreads();
  if (tid == 0)
    __hip_atomic_store(&prog[b], (unsigned)NPOINT, __ATOMIC_RELAXED,
                       __HIP_MEMORY_SCOPE_AGENT);
}

// ---------------- Fallback pair (used only if ws_size < 16) ----------------
__global__ __launch_bounds__(FPS_THREADS)
__attribute__((amdgpu_waves_per_eu(2))) void fps_kernel(
    const float* __restrict__ in, float* __restrict__ out) {
  __shared__ float4 lpxyz[NPTS];
  __shared__ float newb[NPOINT * 3];
  __shared__ alignas(16) u64 slots[2][FPS_WAVES];
  const int b = blockIdx.x;
  const int tid = threadIdx.x;
  const int lane = tid & 63;
  const int wv = tid >> 6;
  const float* base = in + (size_t)b * NPTS * CH;
  v2f pxv[PAIRS], pyv[PAIRS], pzv[PAIRS], dv[PAIRS];
#pragma unroll
  for (int jp = 0; jp < PAIRS; ++jp) {
    int p0 = tid * PTS_PER_THREAD + 2 * jp;
    float4 r0 = *reinterpret_cast<const float4*>(base + (size_t)p0 * CH);
    float4 r1 = *reinterpret_cast<const float4*>(base + (size_t)(p0 + 1) * CH);
    pxv[jp] = (v2f){r0.x, r1.x};
    pyv[jp] = (v2f){r0.y, r1.y};
    pzv[jp] = (v2f){r0.z, r1.z};
    lpxyz[p0] = r0;
    lpxyz[p0 + 1] = r1;
    dv[jp] = (v2f){__builtin_inff(), __builtin_inff()};
  }
  if (tid < FPS_WAVES)
    slots[0][tid] = (tid == 0) ? (((u64)0x7f800000u << 32) | 8191u) : 0ull;
  for (int it = 0; it < NPOINT; ++it) {
    __syncthreads();
    const ulonglong2* sp =
        reinterpret_cast<const ulonglong2*>(&slots[it & 1][0]);
    const ulonglong2 s01 = sp[0];
    const ulonglong2 s23 = sp[1];
    const ulonglong2 s45 = sp[2];
    const ulonglong2 s67 = sp[3];
    u64 ka = (s01.y > s01.x) ? s01.y : s01.x;
    u64 kb = (s23.y > s23.x) ? s23.y : s23.x;
    u64 kc = (s45.y > s45.x) ? s45.y : s45.x;
    u64 kd = (s67.y > s67.x) ? s67.y : s67.x;
    ka = (kb > ka) ? kb : ka;
    kc = (kd > kc) ? kd : kc;
    const u64 k = (kc > ka) ? kc : ka;
    const int gi = 8191 - (int)(unsigned)k;
    const float4 g = lpxyz[gi];
    const float gx = g.x, gy = g.y, gz = g.z;
    if (tid == 0) {
      newb[it * 3 + 0] = gx;
      newb[it * 3 + 1] = gy;
      newb[it * 3 + 2] = gz;
    }
    float bestv = -1.0f;
    float bestx = -1.0f;
    int bestjp = 0;
#pragma unroll
    for (int jp = 0; jp < PAIRS; ++jp) {
      v2f dx = pxv[jp] - gx;
      v2f dy = pyv[jp] - gy;
      v2f dz = pzv[jp] - gz;
      v2f nd = (dx * dx + dy * dy) + dz * dz;
      v2f dn = {fminf(dv[jp].x, nd.x), fminf(dv[jp].y, nd.y)};
      dv[jp] = dn;
      float pm = fmaxf(dn.x, dn.y);
      bool t = pm > bestv;
      bestjp = t ? jp : bestjp;
      bestx = t ? dn.x : bestx;
      bestv = fmaxf(bestv, pm);
    }
    const int bestj = 2 * bestjp + ((bestx == bestv) ? 0 : 1);
    const unsigned besti = (unsigned)(tid * PTS_PER_THREAD + bestj);
    float wm = bestv;
    wm = dpp_fmax<0x111>(wm);
    wm = dpp_fmax<0x112>(wm);
    wm = dpp_fmax<0x114>(wm);
    wm = dpp_fmax<0x118>(wm);
    wm = dpp_fmax<0x142>(wm);
    wm = dpp_fmax<0x143>(wm);
    const float swm =
        __int_as_float(__builtin_amdgcn_readlane(__float_as_int(wm), 63));
    const u64 wbal = __ballot(bestv == swm);
    const int wl = (int)__builtin_ctzll(wbal);
    if (lane == wl) {
      slots[(it + 1) & 1][wv] =
          ((u64)__float_as_uint(bestv) << 32) | (8191u - besti);
    }
  }
  __syncthreads();
  float* ob = out + OFF_NEWXYZ + (size_t)b * NPOINT * 3;
  for (int i = tid; i < NPOINT * 3; i += FPS_THREADS) ob[i] = newb[i];
}

__global__ __launch_bounds__(256) void ballq_kernel(
    const float* __restrict__ in, float* __restrict__ out) {
  const int lane = threadIdx.x & 63;
  const int qid = blockIdx.x * 4 + (threadIdx.x >> 6);
  ballq_one(in, out, qid >> 11, qid & 2047, lane);
}

extern "C" void kernel_launch(void* const* d_in, const int* in_sizes, int n_in,
                              void* d_out, int out_size, void* d_ws,
                              size_t ws_size, hipStream_t stream) {
  (void)in_sizes;
  (void)n_in;
  (void)out_size;
  const float* in = (const float*)d_in[0];
  float* out = (float*)d_out;
  if (d_ws != nullptr && ws_size >= NB * sizeof(unsigned)) {
    unsigned* prog = (unsigned*)d_ws;
    hipMemsetAsync(prog, 0, NB * sizeof(unsigned), stream);
    fused_kernel<<<NB + BQ_BLOCKS, FPS_THREADS, 0, stream>>>(in, out, prog);
  } else {
    fps_kernel<<<NB, FPS_THREADS, 0, stream>>>(in, out);
    ballq_kernel<<<(NB * NPOINT) / 4, 256, 0, stream>>>(in, out);
  }
}

// Round 10
// 1907.843 us; speedup vs baseline: 1.1132x; 1.0013x over previous
//
#include <hip/hip_runtime.h>

// File-scope: forbid implicit fma contraction (keeps every a*b+c as two
// single-rounded IEEE ops, matching the numpy reference bit-for-bit).
#pragma clang fp contract(off)

#define NPOINT 2048
#define NSAMPLE 32
#define NPTS 8192
#define NB 4
#define CH 16
#define FPS_THREADS 512
#define PTS_PER_THREAD (NPTS / FPS_THREADS) /* 16 */
#define PAIRS (PTS_PER_THREAD / 2)          /* 8 */
#define FPS_WAVES (FPS_THREADS / 64)        /* 8 */
#define BQ_BLOCKS 252
#define BQ_WAVES (BQ_BLOCKS * 8) /* 2016 */
#define NWIN (NPOINT / 16)       /* 128 windows per batch */
#define FLAG_STRIDE 16           /* 16 uints = 64B: one line per flag */
#define WS_NEED (NB * NWIN * FLAG_STRIDE * sizeof(unsigned)) /* 32 KB */

typedef unsigned long long u64;
typedef float v2f __attribute__((ext_vector_type(2)));

// Output layout (flat float32, concatenated in reference return order)
#define OFF_NEWXYZ 0
#define OFF_NEWPTS (NB * NPOINT * 3)                          /* 24576 */
#define OFF_IDX (OFF_NEWPTS + NB * NPOINT * NSAMPLE * CH)     /* 4218880 */
#define OFF_GXYZ (OFF_IDX + NB * NPOINT * NSAMPLE)            /* 4481024 */

template <int CTRL>
__device__ __forceinline__ float dpp_fmax(float v) {
  // bound_ctrl=true -> 0-fill; distances are >= 0 so 0 is a safe identity.
  int o = __builtin_amdgcn_update_dpp(0, __float_as_int(v), CTRL, 0xf, 0xf, true);
  return fmaxf(v, __int_as_float(o));
}

// Cache-bypassing (agent-scope, RELAXED) accessors. gfx950 per-XCD L2s are
// non-coherent: agent ACQUIRE emits cache invalidates, agent RELEASE emits
// L2 writebacks (R24: +370us producer convoy). Relaxed agent ops just set
// the sc bits -- direct access to the coherence point, no flush side
// effects. Ordering comes from barriers + in-order issue (see consumers).
__device__ __forceinline__ float ld_sc1(const float* p) {
  return __hip_atomic_load(p, __ATOMIC_RELAXED, __HIP_MEMORY_SCOPE_AGENT);
}
__device__ __forceinline__ void st_sc1(float* p, float v) {
  __hip_atomic_store(p, v, __ATOMIC_RELAXED, __HIP_MEMORY_SCOPE_AGENT);
}

// ---------------- Ball-query per-query body (shared by both paths) ---------
__device__ __forceinline__ void write_slot(float* __restrict__ out,
                                           const float* __restrict__ base,
                                           int b, int qi, int s, int p,
                                           float4 r0, float qx, float qy,
                                           float qz) {
  float dx = __fsub_rn(r0.x, qx);
  float dy = __fsub_rn(r0.y, qy);
  float dz = __fsub_rn(r0.z, qz);
  size_t qs = (size_t)b * NPOINT + qi;
  out[OFF_IDX + qs * NSAMPLE + s] = (float)p;  // idx stored as float32
  float* g = out + OFF_GXYZ + (qs * NSAMPLE + s) * 3;
  g[0] = dx;
  g[1] = dy;
  g[2] = dz;
  const float* row = base + (size_t)p * CH;
  float4 r1 = *reinterpret_cast<const float4*>(row + 4);
  float4 r2 = *reinterpret_cast<const float4*>(row + 8);
  float4 r3 = *reinterpret_cast<const float4*>(row + 12);
  float* np_ = out + OFF_NEWPTS + (qs * NSAMPLE + s) * CH;
  *reinterpret_cast<float4*>(np_ + 0) = make_float4(dx, dy, dz, r0.w);
  *reinterpret_cast<float4*>(np_ + 4) = r1;
  *reinterpret_cast<float4*>(np_ + 8) = r2;
  *reinterpret_cast<float4*>(np_ + 12) = r3;
}

// R23 4-wide chunk-group scan (bit-identical outputs to the serial scan:
// writes gated by pos<NSAMPLE, cnt monotone, 'first' sticky -> up to 3
// extra processed chunks are output-invisible). Query coords are read sc1
// (cache-bypassing -> no stale-L1/L2 hazard, no invalidation cost).
__device__ __forceinline__ void ballq_one(const float* __restrict__ in,
                                          float* __restrict__ out, int b,
                                          int qi, int lane) {
  const float* base = in + (size_t)b * NPTS * CH;
  const float* q = out + OFF_NEWXYZ + ((size_t)b * NPOINT + qi) * 3;
  float qx = ld_sc1(q + 0), qy = ld_sc1(q + 1), qz = ld_sc1(q + 2);
  // Mirror reference: d2 = sum(q*q) + sum(p*p) - 2*(q . p)
  float qn = __fadd_rn(__fadd_rn(__fmul_rn(qx, qx), __fmul_rn(qy, qy)),
                       __fmul_rn(qz, qz));
  int cnt = 0;
  int first = 0;
  bool have_first = false;
  for (int cg = 0; cg < NPTS / 64 && cnt < NSAMPLE; cg += 4) {
    float4 r[4];
#pragma unroll
    for (int u = 0; u < 4; ++u)
      r[u] = *reinterpret_cast<const float4*>(
          base + (size_t)((cg + u) * 64 + lane) * CH);
#pragma unroll
    for (int u = 0; u < 4; ++u) {
      const int chunk = cg + u;
      const int p = chunk * 64 + lane;
      const float4 r0 = r[u];
      float pn =
          __fadd_rn(__fadd_rn(__fmul_rn(r0.x, r0.x), __fmul_rn(r0.y, r0.y)),
                    __fmul_rn(r0.z, r0.z));
      float dot =
          __fadd_rn(__fadd_rn(__fmul_rn(qx, r0.x), __fmul_rn(qy, r0.y)),
                    __fmul_rn(qz, r0.z));
      float d2 = __fsub_rn(__fadd_rn(qn, pn), __fmul_rn(2.0f, dot));
      bool in_r = d2 < 1.0f;  // RADIUS^2
      unsigned long long mask = __ballot(in_r);
      if (!have_first && mask) {
        first = chunk * 64 + __builtin_ctzll(mask);
        have_first = true;
      }
      int pos = cnt + __popcll(mask & ((1ull << lane) - 1ull));
      if (in_r && pos < NSAMPLE)
        write_slot(out, base, b, qi, pos, p, r0, qx, qy, qz);
      cnt += __popcll(mask);
    }
  }
  if (cnt < NSAMPLE) {
    int s = cnt + lane;
    if (s < NSAMPLE) {
      float4 r0 = *reinterpret_cast<const float4*>(base + (size_t)first * CH);
      write_slot(out, base, b, qi, s, first, r0, qx, qy, qz);
    }
  }
}

// ---------------- R26b fused producer-consumer kernel ----------------------
// R25 retro: removing acquire/release cut 2124->1868, but FETCH stayed ~9MB
// (=> that traffic is the consumers' normal input re-reads, NOT invalidates)
// and the producer kept ~+115us. Remaining suspect: ALL 2016 consumer waves
// polled ONE 64B line (prog[0..3]); the producer's flag-store ACK against
// that hammered line landed inside wave 0's next-barrier vmcnt drain.
// R26: one flag line PER WINDOW -- flags[(b*128 + w)*16], 64B apart, 32KB
// workspace. Consumer qi polls only flag[b][qi>>4] (~16-75 pollers/line at
// the frontier); producer's flag store (issued mid-iteration, ~1200cy before
// its barrier, against a lightly-read line) overlaps completely.
// (R26 first submit never compiled -- bad pointer expression in the flag
// store; this is the corrected resubmit, nothing else changed.)
// Protocol (all relaxed sc1, no fences):
//  - it=16k   (k>=1): tids 0..47 sc1-store window k-1 of newb -> newxyz.
//  - barrier at top of it=16k+1 drains those stores (wave-0 vmcnt).
//  - it=16k+1 (k>=1): tid0 sc1-stores flags[b][k-1]=1.
//  - post-loop: window 127 + barrier + flags[b][127]=1.
// Consumer ordering needs no acquire: in-order wave issue (flag load ->
// waitcnt -> branch -> data load) + both sides sc1 (cache-bypassing).
// fps inner loop BYTE-IDENTICAL to the verified 1735us form (ledger: R18
// +152, R19 +385, R20 +1100, R21 +410, R22 +620 -- DO NOT TOUCH).
__global__ __launch_bounds__(FPS_THREADS)
__attribute__((amdgpu_waves_per_eu(2))) void fused_kernel(
    const float* __restrict__ in, float* __restrict__ out,
    unsigned* __restrict__ flags) {
  __shared__ float4 lpxyz[NPTS];      // 128 KB; winner coords: 1 ds_read_b128
  __shared__ float newb[NPOINT * 3];  // 24 KB newxyz staging
  __shared__ alignas(16) u64 slots[2][FPS_WAVES];  // per-wave argmax keys

  const int tid = threadIdx.x;
  const int lane = tid & 63;

  if (blockIdx.x >= NB) {
    // ------------------ ballq consumer role ------------------
    const int slot = (blockIdx.x - NB) * 8 + (tid >> 6);  // 0..2015
    for (int g = slot; g < NB * NPOINT; g += BQ_WAVES) {
      const int qi = g >> 2;  // qi-major: unlocks in production order
      const int b = g & 3;
      const unsigned* fl =
          &flags[(unsigned)(b * NWIN + (qi >> 4)) * FLAG_STRIDE];
      for (;;) {  // wave-uniform spin (b, qi uniform across the wave)
        unsigned f = __hip_atomic_load(fl, __ATOMIC_RELAXED,
                                       __HIP_MEMORY_SCOPE_AGENT);
        if (f) break;
        __builtin_amdgcn_s_sleep(8);  // ~0.2us: ~5 polls/us/wave, spread lines
      }
      ballq_one(in, out, b, qi, lane);
    }
    return;
  }

  // ------------------ fps producer role ------------------
  const int b = blockIdx.x;
  const int wv = tid >> 6;
  const float* base = in + (size_t)b * NPTS * CH;
  float* gnew = out + OFF_NEWXYZ + (size_t)b * NPOINT * 3;
  unsigned* bflags = flags + (unsigned)(b * NWIN) * FLAG_STRIDE;

  v2f pxv[PAIRS], pyv[PAIRS], pzv[PAIRS], dv[PAIRS];
#pragma unroll
  for (int jp = 0; jp < PAIRS; ++jp) {
    int p0 = tid * PTS_PER_THREAD + 2 * jp;
    float4 r0 = *reinterpret_cast<const float4*>(base + (size_t)p0 * CH);
    float4 r1 = *reinterpret_cast<const float4*>(base + (size_t)(p0 + 1) * CH);
    pxv[jp] = (v2f){r0.x, r1.x};
    pyv[jp] = (v2f){r0.y, r1.y};
    pzv[jp] = (v2f){r0.z, r1.z};
    lpxyz[p0] = r0;
    lpxyz[p0 + 1] = r1;
    dv[jp] = (v2f){__builtin_inff(), __builtin_inff()};
  }
  // Prime parity-0 slots: slot 0 = (+inf, idx 0) wins the first compare.
  if (tid < FPS_WAVES)
    slots[0][tid] = (tid == 0) ? (((u64)0x7f800000u << 32) | 8191u) : 0ull;

  for (int it = 0; it < NPOINT; ++it) {
    __syncthreads();  // separates slot writes (it-1) from reads (it);
                      // also drains the previous window's publish stores
    // Read all 8 wave keys (broadcast, 4x ds_read_b128), 7-compare u64 max.
    const ulonglong2* sp =
        reinterpret_cast<const ulonglong2*>(&slots[it & 1][0]);
    const ulonglong2 s01 = sp[0];
    const ulonglong2 s23 = sp[1];
    const ulonglong2 s45 = sp[2];
    const ulonglong2 s67 = sp[3];
    u64 ka = (s01.y > s01.x) ? s01.y : s01.x;
    u64 kb = (s23.y > s23.x) ? s23.y : s23.x;
    u64 kc = (s45.y > s45.x) ? s45.y : s45.x;
    u64 kd = (s67.y > s67.x) ? s67.y : s67.x;
    ka = (kb > ka) ? kb : ka;
    kc = (kd > kc) ? kd : kc;
    const u64 k = (kc > ka) ? kc : ka;
    const int gi = 8191 - (int)(unsigned)k;  // low 32 bits = 8191-idx
    // Winner coords: broadcast LDS read.
    const float4 g = lpxyz[gi];
    const float gx = g.x, gy = g.y, gz = g.z;
    if (tid == 0) {
      newb[it * 3 + 0] = gx;
      newb[it * 3 + 1] = gy;
      newb[it * 3 + 2] = gz;
    }
    // Windowed publish (off the critical dataflow; relaxed sc1, no fences).
    if ((it & 15) == 0 && it >= 16 && tid < 48)
      st_sc1(&gnew[(it - 16) * 3 + tid], newb[(it - 16) * 3 + tid]);
    if ((it & 15) == 1 && it > 16 && tid == 0)
      __hip_atomic_store(&bflags[((it >> 4) - 1) * FLAG_STRIDE], 1u,
                         __ATOMIC_RELAXED, __HIP_MEMORY_SCOPE_AGENT);
    // Distance update (packed pairs; exact IEEE per-element) + in-loop
    // pair-granular tracking (bestjp + bestx; hidden under loop ILP).
    float bestv = -1.0f;
    float bestx = -1.0f;
    int bestjp = 0;
#pragma unroll
    for (int jp = 0; jp < PAIRS; ++jp) {
      v2f dx = pxv[jp] - gx;
      v2f dy = pyv[jp] - gy;
      v2f dz = pzv[jp] - gz;
      v2f nd = (dx * dx + dy * dy) + dz * dz;
      v2f dn = {fminf(dv[jp].x, nd.x), fminf(dv[jp].y, nd.y)};
      dv[jp] = dn;
      float pm = fmaxf(dn.x, dn.y);
      bool t = pm > bestv;  // strict: lowest jp wins ties
      bestjp = t ? jp : bestjp;
      bestx = t ? dn.x : bestx;
      bestv = fmaxf(bestv, pm);
    }
    // Within-pair parity: .x first (lower index) on ties.
    const int bestj = 2 * bestjp + ((bestx == bestv) ? 0 : 1);
    const unsigned besti = (unsigned)(tid * PTS_PER_THREAD + bestj);
    // Wave max via 6 DPP rounds -> lane 63; ballot -> lowest matching lane.
    float wm = bestv;
    wm = dpp_fmax<0x111>(wm);  // row_shr:1
    wm = dpp_fmax<0x112>(wm);  // row_shr:2
    wm = dpp_fmax<0x114>(wm);  // row_shr:4
    wm = dpp_fmax<0x118>(wm);  // row_shr:8
    wm = dpp_fmax<0x142>(wm);  // row_bcast15
    wm = dpp_fmax<0x143>(wm);  // row_bcast31
    const float swm =
        __int_as_float(__builtin_amdgcn_readlane(__float_as_int(wm), 63));
    const u64 wbal = __ballot(bestv == swm);
    const int wl = (int)__builtin_ctzll(wbal);
    if (lane == wl) {  // tiny tail: pack + one ds_write_b64
      slots[(it + 1) & 1][wv] =
          ((u64)__float_as_uint(bestv) << 32) | (8191u - besti);
    }
  }
  __syncthreads();
  // Final window [2032, 2048): sc1 store, drain via barrier, flag.
  if (tid < 48) st_sc1(&gnew[2032 * 3 + tid], newb[2032 * 3 + tid]);
  __syncthreads();
  if (tid == 0)
    __hip_atomic_store(&bflags[(NWIN - 1) * FLAG_STRIDE], 1u, __ATOMIC_RELAXED,
                       __HIP_MEMORY_SCOPE_AGENT);
}

// ---------------- Fallback pair (used only if ws too small) ----------------
__global__ __launch_bounds__(FPS_THREADS)
__attribute__((amdgpu_waves_per_eu(2))) void fps_kernel(
    const float* __restrict__ in, float* __restrict__ out) {
  __shared__ float4 lpxyz[NPTS];
  __shared__ float newb[NPOINT * 3];
  __shared__ alignas(16) u64 slots[2][FPS_WAVES];
  const int b = blockIdx.x;
  const int tid = threadIdx.x;
  const int lane = tid & 63;
  const int wv = tid >> 6;
  const float* base = in + (size_t)b * NPTS * CH;
  v2f pxv[PAIRS], pyv[PAIRS], pzv[PAIRS], dv[PAIRS];
#pragma unroll
  for (int jp = 0; jp < PAIRS; ++jp) {
    int p0 = tid * PTS_PER_THREAD + 2 * jp;
    float4 r0 = *reinterpret_cast<const float4*>(base + (size_t)p0 * CH);
    float4 r1 = *reinterpret_cast<const float4*>(base + (size_t)(p0 + 1) * CH);
    pxv[jp] = (v2f){r0.x, r1.x};
    pyv[jp] = (v2f){r0.y, r1.y};
    pzv[jp] = (v2f){r0.z, r1.z};
    lpxyz[p0] = r0;
    lpxyz[p0 + 1] = r1;
    dv[jp] = (v2f){__builtin_inff(), __builtin_inff()};
  }
  if (tid < FPS_WAVES)
    slots[0][tid] = (tid == 0) ? (((u64)0x7f800000u << 32) | 8191u) : 0ull;
  for (int it = 0; it < NPOINT; ++it) {
    __syncthreads();
    const ulonglong2* sp =
        reinterpret_cast<const ulonglong2*>(&slots[it & 1][0]);
    const ulonglong2 s01 = sp[0];
    const ulonglong2 s23 = sp[1];
    const ulonglong2 s45 = sp[2];
    const ulonglong2 s67 = sp[3];
    u64 ka = (s01.y > s01.x) ? s01.y : s01.x;
    u64 kb = (s23.y > s23.x) ? s23.y : s23.x;
    u64 kc = (s45.y > s45.x) ? s45.y : s45.x;
    u64 kd = (s67.y > s67.x) ? s67.y : s67.x;
    ka = (kb > ka) ? kb : ka;
    kc = (kd > kc) ? kd : kc;
    const u64 k = (kc > ka) ? kc : ka;
    const int gi = 8191 - (int)(unsigned)k;
    const float4 g = lpxyz[gi];
    const float gx = g.x, gy = g.y, gz = g.z;
    if (tid == 0) {
      newb[it * 3 + 0] = gx;
      newb[it * 3 + 1] = gy;
      newb[it * 3 + 2] = gz;
    }
    float bestv = -1.0f;
    float bestx = -1.0f;
    int bestjp = 0;
#pragma unroll
    for (int jp = 0; jp < PAIRS; ++jp) {
      v2f dx = pxv[jp] - gx;
      v2f dy = pyv[jp] - gy;
      v2f dz = pzv[jp] - gz;
      v2f nd = (dx * dx + dy * dy) + dz * dz;
      v2f dn = {fminf(dv[jp].x, nd.x), fminf(dv[jp].y, nd.y)};
      dv[jp] = dn;
      float pm = fmaxf(dn.x, dn.y);
      bool t = pm > bestv;
      bestjp = t ? jp : bestjp;
      bestx = t ? dn.x : bestx;
      bestv = fmaxf(bestv, pm);
    }
    const int bestj = 2 * bestjp + ((bestx == bestv) ? 0 : 1);
    const unsigned besti = (unsigned)(tid * PTS_PER_THREAD + bestj);
    float wm = bestv;
    wm = dpp_fmax<0x111>(wm);
    wm = dpp_fmax<0x112>(wm);
    wm = dpp_fmax<0x114>(wm);
    wm = dpp_fmax<0x118>(wm);
    wm = dpp_fmax<0x142>(wm);
    wm = dpp_fmax<0x143>(wm);
    const float swm =
        __int_as_float(__builtin_amdgcn_readlane(__float_as_int(wm), 63));
    const u64 wbal = __ballot(bestv == swm);
    const int wl = (int)__builtin_ctzll(wbal);
    if (lane == wl) {
      slots[(it + 1) & 1][wv] =
          ((u64)__float_as_uint(bestv) << 32) | (8191u - besti);
    }
  }
  __syncthreads();
  float* ob = out + OFF_NEWXYZ + (size_t)b * NPOINT * 3;
  for (int i = tid; i < NPOINT * 3; i += FPS_THREADS) ob[i] = newb[i];
}

__global__ __launch_bounds__(256) void ballq_kernel(
    const float* __restrict__ in, float* __restrict__ out) {
  const int lane = threadIdx.x & 63;
  const int qid = blockIdx.x * 4 + (threadIdx.x >> 6);
  ballq_one(in, out, qid >> 11, qid & 2047, lane);
}

extern "C" void kernel_launch(void* const* d_in, const int* in_sizes, int n_in,
                              void* d_out, int out_size, void* d_ws,
                              size_t ws_size, hipStream_t stream) {
  (void)in_sizes;
  (void)n_in;
  (void)out_size;
  const float* in = (const float*)d_in[0];
  float* out = (float*)d_out;
  if (d_ws != nullptr && ws_size >= WS_NEED) {
    unsigned* flags = (unsigned*)d_ws;
    hipMemsetAsync(flags, 0, WS_NEED, stream);
    fused_kernel<<<NB + BQ_BLOCKS, FPS_THREADS, 0, stream>>>(in, out, flags);
  } else {
    fps_kernel<<<NB, FPS_THREADS, 0, stream>>>(in, out);
    ballq_kernel<<<(NB * NPOINT) / 4, 256, 0, stream>>>(in, out);
  }
}

// Round 11
// 1747.536 us; speedup vs baseline: 1.2153x; 1.0917x over previous
//
#include <hip/hip_runtime.h>

// File-scope: forbid implicit fma contraction (keeps every a*b+c as two
// single-rounded IEEE ops, matching the numpy reference bit-for-bit).
#pragma clang fp contract(off)

#define NPOINT 2048
#define NSAMPLE 32
#define NPTS 8192
#define NB 4
#define CH 16
#define FPS_THREADS 512
#define PTS_PER_THREAD (NPTS / FPS_THREADS) /* 16 */
#define PAIRS (PTS_PER_THREAD / 2)          /* 8 */
#define FPS_WAVES (FPS_THREADS / 64)        /* 8 */
#define BQ_BLOCKS 252
#define BQ_WAVES (BQ_BLOCKS * 8) /* 2016 */
#define SENT 0xFFFFFFFFu /* -NaN: unreachable by Gaussian input, memset-able */

typedef unsigned long long u64;
typedef float v2f __attribute__((ext_vector_type(2)));

// Output layout (flat float32, concatenated in reference return order)
#define OFF_NEWXYZ 0
#define OFF_NEWPTS (NB * NPOINT * 3)                          /* 24576 */
#define OFF_IDX (OFF_NEWPTS + NB * NPOINT * NSAMPLE * CH)     /* 4218880 */
#define OFF_GXYZ (OFF_IDX + NB * NPOINT * NSAMPLE)            /* 4481024 */

template <int CTRL>
__device__ __forceinline__ float dpp_fmax(float v) {
  // bound_ctrl=true -> 0-fill; distances are >= 0 so 0 is a safe identity.
  int o = __builtin_amdgcn_update_dpp(0, __float_as_int(v), CTRL, 0xf, 0xf, true);
  return fmaxf(v, __int_as_float(o));
}

// Workgroup barrier WITHOUT the vmcnt(0) drain __syncthreads carries.
// LDS cross-wave correctness only needs each wave's own ds ops complete
// before s_barrier (lgkmcnt); global sc1 publish stores stay in flight
// across barriers. This removes the R25/R26 residual: wave 0's 48-store
// ACK (~2-3k cy at the coherence point) was drained inside __syncthreads'
// vmcnt(0) every window, convoying all 8 waves (~130us/2048 iters).
__device__ __forceinline__ void lgkm_barrier() {
  asm volatile("s_waitcnt lgkmcnt(0)" ::: "memory");
  __builtin_amdgcn_s_barrier();
}

// Cache-bypassing (agent-scope, RELAXED) accessors. gfx950 per-XCD L2s are
// non-coherent: agent ACQUIRE emits cache invalidates, agent RELEASE emits
// L2 writebacks (R24: +370us producer convoy). Relaxed agent ops just set
// the sc bits -- direct access to the coherence point, no flush side
// effects. Word-granular sentinel coding makes ordering irrelevant.
__device__ __forceinline__ void st_sc1(float* p, float v) {
  __hip_atomic_store(p, v, __ATOMIC_RELAXED, __HIP_MEMORY_SCOPE_AGENT);
}
__device__ __forceinline__ unsigned ld_sc1_u(const unsigned* p) {
  return __hip_atomic_load(p, __ATOMIC_RELAXED, __HIP_MEMORY_SCOPE_AGENT);
}

// ---------------- Ball-query per-query body ---------------------------------
__device__ __forceinline__ void write_slot(float* __restrict__ out,
                                           const float* __restrict__ base,
                                           int b, int qi, int s, int p,
                                           float4 r0, float qx, float qy,
                                           float qz) {
  float dx = __fsub_rn(r0.x, qx);
  float dy = __fsub_rn(r0.y, qy);
  float dz = __fsub_rn(r0.z, qz);
  size_t qs = (size_t)b * NPOINT + qi;
  out[OFF_IDX + qs * NSAMPLE + s] = (float)p;  // idx stored as float32
  float* g = out + OFF_GXYZ + (qs * NSAMPLE + s) * 3;
  g[0] = dx;
  g[1] = dy;
  g[2] = dz;
  const float* row = base + (size_t)p * CH;
  float4 r1 = *reinterpret_cast<const float4*>(row + 4);
  float4 r2 = *reinterpret_cast<const float4*>(row + 8);
  float4 r3 = *reinterpret_cast<const float4*>(row + 12);
  float* np_ = out + OFF_NEWPTS + (qs * NSAMPLE + s) * CH;
  *reinterpret_cast<float4*>(np_ + 0) = make_float4(dx, dy, dz, r0.w);
  *reinterpret_cast<float4*>(np_ + 4) = r1;
  *reinterpret_cast<float4*>(np_ + 8) = r2;
  *reinterpret_cast<float4*>(np_ + 12) = r3;
}

// R23 4-wide chunk-group scan (bit-identical outputs to the serial scan:
// writes gated by pos<NSAMPLE, cnt monotone, 'first' sticky -> up to 3
// extra processed chunks are output-invisible). Coords passed in (the
// fused consumer already holds them from the sentinel poll).
__device__ __forceinline__ void ballq_one(const float* __restrict__ in,
                                          float* __restrict__ out, int b,
                                          int qi, int lane, float qx,
                                          float qy, float qz) {
  const float* base = in + (size_t)b * NPTS * CH;
  // Mirror reference: d2 = sum(q*q) + sum(p*p) - 2*(q . p)
  float qn = __fadd_rn(__fadd_rn(__fmul_rn(qx, qx), __fmul_rn(qy, qy)),
                       __fmul_rn(qz, qz));
  int cnt = 0;
  int first = 0;
  bool have_first = false;
  for (int cg = 0; cg < NPTS / 64 && cnt < NSAMPLE; cg += 4) {
    float4 r[4];
#pragma unroll
    for (int u = 0; u < 4; ++u)
      r[u] = *reinterpret_cast<const float4*>(
          base + (size_t)((cg + u) * 64 + lane) * CH);
#pragma unroll
    for (int u = 0; u < 4; ++u) {
      const int chunk = cg + u;
      const int p = chunk * 64 + lane;
      const float4 r0 = r[u];
      float pn =
          __fadd_rn(__fadd_rn(__fmul_rn(r0.x, r0.x), __fmul_rn(r0.y, r0.y)),
                    __fmul_rn(r0.z, r0.z));
      float dot =
          __fadd_rn(__fadd_rn(__fmul_rn(qx, r0.x), __fmul_rn(qy, r0.y)),
                    __fmul_rn(qz, r0.z));
      float d2 = __fsub_rn(__fadd_rn(qn, pn), __fmul_rn(2.0f, dot));
      bool in_r = d2 < 1.0f;  // RADIUS^2
      unsigned long long mask = __ballot(in_r);
      if (!have_first && mask) {
        first = chunk * 64 + __builtin_ctzll(mask);
        have_first = true;
      }
      int pos = cnt + __popcll(mask & ((1ull << lane) - 1ull));
      if (in_r && pos < NSAMPLE)
        write_slot(out, base, b, qi, pos, p, r0, qx, qy, qz);
      cnt += __popcll(mask);
    }
  }
  if (cnt < NSAMPLE) {
    int s = cnt + lane;
    if (s < NSAMPLE) {
      float4 r0 = *reinterpret_cast<const float4*>(base + (size_t)first * CH);
      write_slot(out, base, b, qi, s, first, r0, qx, qy, qz);
    }
  }
}

// ---------------- R27 fused kernel: sentinel-coded, drain-free --------------
// Grid = 4 fps blocks + 252 ballq blocks = 256; 131KB static LDS -> exactly
// 1 block/CU -> all 256 co-resident (validated by R24-R26: passed, no hang).
//
// Producer (blocks 0..3): inner loop BYTE-IDENTICAL to the verified 1735us
// form (ledger: R18 +152, R19 +385, R20 +1100, R21 +410, R22 +620 -- every
// instruction-stream perturbation regressed; DO NOT TOUCH). Differences are
// confined to the tid0-only slot (was: newb LDS write; now: 3 sc1 stores)
// and the barrier flavor (lgkm_barrier, no vmcnt drain -- see above).
// newxyz output region is pre-poisoned with SENT (0xFF memset); tid0
// publishes each winner's 3 words at iteration it; a word is written once,
// word-atomic -> the data IS the readiness flag, no ordering needed, no
// window flags, no workspace, no epilogue dump.
// Consumers (blocks 4..255): 2016 waves, qi-major (g=qi*4+b) matching
// production order; poll own query's 3 words != SENT (relaxed sc1 +
// s_sleep), then run the R23 query body with the polled coords.
// Tie-breaks unchanged (exact jnp.argmax lowest-index semantics).
__global__ __launch_bounds__(FPS_THREADS)
__attribute__((amdgpu_waves_per_eu(2))) void fused_kernel(
    const float* __restrict__ in, float* __restrict__ out) {
  __shared__ float4 lpxyz[NPTS];  // 128 KB; winner coords: 1 ds_read_b128
  __shared__ alignas(16) u64 slots[2][FPS_WAVES];  // per-wave argmax keys

  const int tid = threadIdx.x;
  const int lane = tid & 63;

  if (blockIdx.x >= NB) {
    // ------------------ ballq consumer role ------------------
    const int slot = (blockIdx.x - NB) * 8 + (tid >> 6);  // 0..2015
    for (int g = slot; g < NB * NPOINT; g += BQ_WAVES) {
      const int qi = g >> 2;  // qi-major: unlocks in production order
      const int b = g & 3;
      const unsigned* qw = reinterpret_cast<const unsigned*>(
          out + OFF_NEWXYZ + ((size_t)b * NPOINT + qi) * 3);
      unsigned x, y, z;
      for (;;) {  // wave-uniform spin (b, qi uniform across the wave)
        x = ld_sc1_u(&qw[0]);
        y = ld_sc1_u(&qw[1]);
        z = ld_sc1_u(&qw[2]);
        if (x != SENT && y != SENT && z != SENT) break;
        __builtin_amdgcn_s_sleep(8);  // ~0.2us between polls
      }
      ballq_one(in, out, b, qi, lane, __uint_as_float(x), __uint_as_float(y),
                __uint_as_float(z));
    }
    return;
  }

  // ------------------ fps producer role ------------------
  const int b = blockIdx.x;
  const int wv = tid >> 6;
  const float* base = in + (size_t)b * NPTS * CH;
  float* gnew = out + OFF_NEWXYZ + (size_t)b * NPOINT * 3;

  v2f pxv[PAIRS], pyv[PAIRS], pzv[PAIRS], dv[PAIRS];
#pragma unroll
  for (int jp = 0; jp < PAIRS; ++jp) {
    int p0 = tid * PTS_PER_THREAD + 2 * jp;
    float4 r0 = *reinterpret_cast<const float4*>(base + (size_t)p0 * CH);
    float4 r1 = *reinterpret_cast<const float4*>(base + (size_t)(p0 + 1) * CH);
    pxv[jp] = (v2f){r0.x, r1.x};
    pyv[jp] = (v2f){r0.y, r1.y};
    pzv[jp] = (v2f){r0.z, r1.z};
    lpxyz[p0] = r0;
    lpxyz[p0 + 1] = r1;
    dv[jp] = (v2f){__builtin_inff(), __builtin_inff()};
  }
  // Prime parity-0 slots: slot 0 = (+inf, idx 0) wins the first compare.
  if (tid < FPS_WAVES)
    slots[0][tid] = (tid == 0) ? (((u64)0x7f800000u << 32) | 8191u) : 0ull;

  for (int it = 0; it < NPOINT; ++it) {
    lgkm_barrier();  // separates slot writes (it-1) from reads (it);
                     // LDS-only drain -- publish stores stay in flight
    // Read all 8 wave keys (broadcast, 4x ds_read_b128), 7-compare u64 max.
    const ulonglong2* sp =
        reinterpret_cast<const ulonglong2*>(&slots[it & 1][0]);
    const ulonglong2 s01 = sp[0];
    const ulonglong2 s23 = sp[1];
    const ulonglong2 s45 = sp[2];
    const ulonglong2 s67 = sp[3];
    u64 ka = (s01.y > s01.x) ? s01.y : s01.x;
    u64 kb = (s23.y > s23.x) ? s23.y : s23.x;
    u64 kc = (s45.y > s45.x) ? s45.y : s45.x;
    u64 kd = (s67.y > s67.x) ? s67.y : s67.x;
    ka = (kb > ka) ? kb : ka;
    kc = (kd > kc) ? kd : kc;
    const u64 k = (kc > ka) ? kc : ka;
    const int gi = 8191 - (int)(unsigned)k;  // low 32 bits = 8191-idx
    // Winner coords: broadcast LDS read.
    const float4 g = lpxyz[gi];
    const float gx = g.x, gy = g.y, gz = g.z;
    if (tid == 0) {  // publish winner: 3 sc1 dwords, fire-and-forget
      st_sc1(&gnew[it * 3 + 0], gx);
      st_sc1(&gnew[it * 3 + 1], gy);
      st_sc1(&gnew[it * 3 + 2], gz);
    }
    // Distance update (packed pairs; exact IEEE per-element) + in-loop
    // pair-granular tracking (bestjp + bestx; hidden under loop ILP).
    float bestv = -1.0f;
    float bestx = -1.0f;
    int bestjp = 0;
#pragma unroll
    for (int jp = 0; jp < PAIRS; ++jp) {
      v2f dx = pxv[jp] - gx;
      v2f dy = pyv[jp] - gy;
      v2f dz = pzv[jp] - gz;
      v2f nd = (dx * dx + dy * dy) + dz * dz;
      v2f dn = {fminf(dv[jp].x, nd.x), fminf(dv[jp].y, nd.y)};
      dv[jp] = dn;
      float pm = fmaxf(dn.x, dn.y);
      bool t = pm > bestv;  // strict: lowest jp wins ties
      bestjp = t ? jp : bestjp;
      bestx = t ? dn.x : bestx;
      bestv = fmaxf(bestv, pm);
    }
    // Within-pair parity: .x first (lower index) on ties.
    const int bestj = 2 * bestjp + ((bestx == bestv) ? 0 : 1);
    const unsigned besti = (unsigned)(tid * PTS_PER_THREAD + bestj);
    // Wave max via 6 DPP rounds -> lane 63; ballot -> lowest matching lane.
    float wm = bestv;
    wm = dpp_fmax<0x111>(wm);  // row_shr:1
    wm = dpp_fmax<0x112>(wm);  // row_shr:2
    wm = dpp_fmax<0x114>(wm);  // row_shr:4
    wm = dpp_fmax<0x118>(wm);  // row_shr:8
    wm = dpp_fmax<0x142>(wm);  // row_bcast15
    wm = dpp_fmax<0x143>(wm);  // row_bcast31
    const float swm =
        __int_as_float(__builtin_amdgcn_readlane(__float_as_int(wm), 63));
    const u64 wbal = __ballot(bestv == swm);
    const int wl = (int)__builtin_ctzll(wbal);
    if (lane == wl) {  // tiny tail: pack + one ds_write_b64
      slots[(it + 1) & 1][wv] =
          ((u64)__float_as_uint(bestv) << 32) | (8191u - besti);
    }
  }
  // No epilogue: newxyz fully published in-loop; dispatch completion
  // guarantees all stores retire before host readback.
}

extern "C" void kernel_launch(void* const* d_in, const int* in_sizes, int n_in,
                              void* d_out, int out_size, void* d_ws,
                              size_t ws_size, hipStream_t stream) {
  (void)in_sizes;
  (void)n_in;
  (void)out_size;
  (void)d_ws;
  (void)ws_size;
  const float* in = (const float*)d_in[0];
  float* out = (float*)d_out;
  // Poison newxyz with SENT (0xFF bytes = -NaN) so data doubles as the
  // readiness flag. Stream-ordered: completes before the kernel starts.
  hipMemsetAsync(out + OFF_NEWXYZ, 0xFF, (size_t)NB * NPOINT * 3 * sizeof(float),
                 stream);
  fused_kernel<<<NB + BQ_BLOCKS, FPS_THREADS, 0, stream>>>(in, out);
}